// Round 10
// baseline (792.714 us; speedup 1.0000x reference)
//
#include <hip/hip_runtime.h>
#include <hip/hip_fp16.h>

// ---------------- constants ----------------
namespace {
constexpr int NN = 50000;   // nodes
constexpr int NE = 800000;  // edges
constexpr int NG = 256;     // graphs
constexpr int NF = 34;      // in features
constexpr int NL = 4;       // GAT layers
constexpr int NB = (NN + 255) / 256;  // scan blocks = 196
constexpr int STS = 32;     // stats slot spread
constexpr int GQ = ((NE + 3) / 4 + 255) / 256;   // 782 fill blocks
constexpr int GD = ((NE + 7) / 8 + 255) / 256;   // 391 deg blocks (8 strands)
constexpr int GE = (NN + 63) / 64;               // 782 emb blocks
}
#define EPSB 1e-5f
#define LSLOPE 0.2f
#define INV_SQRT_C 0.17677669529663687f  // 1/sqrt(32)

typedef short bf16x8 __attribute__((ext_vector_type(8)));
typedef float f32x4 __attribute__((ext_vector_type(4)));
typedef _Float16 hv2 __attribute__((ext_vector_type(2)));

static __device__ __forceinline__ short f2bf(float f) {
    unsigned int u = __float_as_uint(f);
    u = (u + 0x7fff + ((u >> 16) & 1)) >> 16;  // RNE
    return (short)u;
}
// order-preserving float<->uint for atomicMax; all encodings > 0, so memset-0 = -inf
static __device__ __forceinline__ unsigned fenc(float x) {
    unsigned u = __float_as_uint(x);
    return (u & 0x80000000u) ? ~u : (u | 0x80000000u);
}
static __device__ __forceinline__ float fdec(unsigned u) {
    return __uint_as_float((u & 0x80000000u) ? (u ^ 0x80000000u) : ~u);
}
// v_dot2_f32_f16: c += a.x*b.x + a.y*b.y (fp32 accumulate)
static __device__ __forceinline__ float fdot2(hv2 a, hv2 b, float c) {
    return __builtin_amdgcn_fdot2(a, b, c, false);
}

// ---------------- degree histogram: 8 DISJOINT strands/thread (max atomic MLP) ------
__global__ __launch_bounds__(256) void k_deg(const int* __restrict__ ei,
                                             int* __restrict__ deg,
                                             int* __restrict__ rank) {
    int tid = blockIdx.x * 256 + threadIdx.x;
    const int S = (NE + 7) / 8;  // 100000
    if (tid >= S) return;
#pragma unroll
    for (int k = 0; k < 8; ++k) {
        int e = tid + k * S;
        if (e < NE) rank[e] = atomicAdd(&deg[ei[NE + e]], 1);
    }
}

// ---------------- MERGED front-end: weight prep + embedding GEMM (fp16 out) --------
__global__ __launch_bounds__(256) void k_init(const float* __restrict__ gWl,
                                              const float* __restrict__ gWr,
                                              const float* __restrict__ tWq,
                                              const float* __restrict__ tWk,
                                              const float* __restrict__ tWv,
                                              const float* __restrict__ tWs,
                                              short* __restrict__ Wt,
                                              const float* __restrict__ A,
                                              const float* __restrict__ W,
                                              const float* __restrict__ bias,
                                              __half* __restrict__ outEmb,
                                              float* __restrict__ stms) {
    __shared__ float As[64 * NF];
    __shared__ float sred[256];
    int blk = blockIdx.x;
    if (blk < 12) {  // ---- weight prep: (128,128) fp32 -> transposed bf16
        const float* src;
        if (blk < 4) src = gWl + blk * 16384;
        else if (blk < 8) src = gWr + (blk - 4) * 16384;
        else if (blk == 8) src = tWq;
        else if (blk == 9) src = tWk;
        else if (blk == 10) src = tWv;
        else src = tWs;
        short* d = Wt + blk * 16384;
        for (int i = threadIdx.x; i < 16384; i += 256) {
            int n = i >> 7, k = i & 127;
            d[i] = f2bf(src[k * 128 + n]);  // Wt[n][k] = W[k][n]
        }
        return;
    }
    blk -= 12;
    // ---- embedding GEMM (n,34)@(34,128)+bias, fp16 out, fused col-stats
    int r0 = blk * 64;
    int rows = NN - r0; if (rows > 64) rows = 64;
    int total = rows * NF;
    for (int idx = threadIdx.x; idx < 64 * NF; idx += 256)
        As[idx] = (idx < total) ? A[(size_t)r0 * NF + idx] : 0.f;
    sred[threadIdx.x] = 0.f;
    __syncthreads();
    int tx = threadIdx.x & 31, ty = threadIdx.x >> 5;
    const float4* W4 = (const float4*)W;
    float acc[8][4];
#pragma unroll
    for (int j = 0; j < 8; ++j)
#pragma unroll
        for (int i = 0; i < 4; ++i) acc[j][i] = 0.f;
#pragma unroll 2
    for (int k = 0; k < NF; ++k) {
        float4 w = W4[k * 32 + tx];
#pragma unroll
        for (int j = 0; j < 8; ++j) {
            float a = As[(ty * 8 + j) * NF + k];
            acc[j][0] += a * w.x; acc[j][1] += a * w.y;
            acc[j][2] += a * w.z; acc[j][3] += a * w.w;
        }
    }
    float4 b = ((const float4*)bias)[tx];
    float s[4] = {0.f, 0.f, 0.f, 0.f}, ss[4] = {0.f, 0.f, 0.f, 0.f};
#pragma unroll
    for (int j = 0; j < 8; ++j) {
        int r = ty * 8 + j;
        if (r < rows) {
            float4 o = make_float4(acc[j][0] + b.x, acc[j][1] + b.y,
                                   acc[j][2] + b.z, acc[j][3] + b.w);
            union { short4 s4; __half h[4]; } uh;
            uh.h[0] = __float2half(o.x); uh.h[1] = __float2half(o.y);
            uh.h[2] = __float2half(o.z); uh.h[3] = __float2half(o.w);
            *(short4*)&outEmb[(size_t)(r0 + r) * 128 + tx * 4] = uh.s4;
            s[0] += o.x; ss[0] += o.x * o.x;
            s[1] += o.y; ss[1] += o.y * o.y;
            s[2] += o.z; ss[2] += o.z * o.z;
            s[3] += o.w; ss[3] += o.w * o.w;
        }
    }
#pragma unroll
    for (int i = 0; i < 4; ++i) {
        atomicAdd(&sred[tx * 4 + i], s[i]);
        atomicAdd(&sred[128 + tx * 4 + i], ss[i]);
    }
    __syncthreads();
    atomicAdd(&stms[(blk & (STS - 1)) * 256 + threadIdx.x], sred[threadIdx.x]);
}

__global__ __launch_bounds__(256) void k_scan1(const int* __restrict__ deg, int* __restrict__ bsum) {
    __shared__ int sm[256];
    int i = blockIdx.x * 256 + threadIdx.x;
    sm[threadIdx.x] = (i < NN) ? deg[i] : 0;
    __syncthreads();
    for (int off = 128; off > 0; off >>= 1) {
        if (threadIdx.x < off) sm[threadIdx.x] += sm[threadIdx.x + off];
        __syncthreads();
    }
    if (threadIdx.x == 0) bsum[blockIdx.x] = sm[0];
}

__global__ __launch_bounds__(256) void k_scan2(const int* __restrict__ bsum,
                                               int* __restrict__ boff, int* __restrict__ rp) {
    __shared__ int sm[256];
    int t = threadIdx.x;
    int v = (t < NB) ? bsum[t] : 0;
    sm[t] = v;
    __syncthreads();
    for (int off = 1; off < 256; off <<= 1) {
        int u = (t >= off) ? sm[t - off] : 0;
        __syncthreads();
        sm[t] += u;
        __syncthreads();
    }
    if (t < NB) boff[t] = sm[t] - v;
    if (t == 255) rp[NN] = sm[255];
}

__global__ __launch_bounds__(256) void k_scan3(const int* __restrict__ deg,
                                               const int* __restrict__ boff,
                                               int* __restrict__ rp) {
    __shared__ int sm[256];
    int i = blockIdx.x * 256 + threadIdx.x;
    int t = threadIdx.x;
    int v = (i < NN) ? deg[i] : 0;
    sm[t] = v;
    __syncthreads();
    for (int off = 1; off < 256; off <<= 1) {
        int u = (t >= off) ? sm[t - off] : 0;
        __syncthreads();
        sm[t] += u;
        __syncthreads();
    }
    if (i < NN) rp[i] = boff[blockIdx.x] + sm[t] - v;
}

// atomic-free scatter: p = rp[d] + rank[e]; src-only
__global__ __launch_bounds__(256) void k_fill(const int* __restrict__ ei,
                                              const int* __restrict__ rp,
                                              const int* __restrict__ rank,
                                              int* __restrict__ esrc) {
    int tid = blockIdx.x * 256 + threadIdx.x;
    const int S = (NE + 3) / 4;
    if (tid >= S) return;
#pragma unroll
    for (int k = 0; k < 4; ++k) {
        int e = tid + k * S;
        if (e < NE) {
            int s = ei[e];
            int d = ei[NE + e];
            int p = rp[d] + rank[e];
            esrc[p] = s;
        }
    }
}

// ---------------- BN statistics over fp16 bC (slot-spread) -----------
__global__ __launch_bounds__(256) void k_stats(const __half* __restrict__ src, int nRows,
                                               float* __restrict__ st) {
    int c = threadIdx.x & 127;
    int sub = threadIdx.x >> 7;  // 0/1
    int r0 = blockIdx.x * 128;
    int rend = r0 + 128; if (rend > nRows) rend = nRows;
    float s = 0.f, ss = 0.f;
    for (int r = r0 + sub; r < rend; r += 2) {
        float v = __half2float(src[(size_t)r * 128 + c]);
        s += v; ss += v * v;
    }
    float* dst = st + (blockIdx.x & (STS - 1)) * 256;
    atomicAdd(&dst[c], s);
    atomicAdd(&dst[128 + c], ss);
}

// ------- pair-fused MFMA GEMM, 128-row tile (r6-proven) with BN(+ReLU)+residual ----
// SRC16: src buffer is fp16; else fp32. st = STS slot-spread stats.
template <int SRC16, int OUTH0, int OUTH1, int RES, int XOUT>
__global__ __launch_bounds__(256) void k_gemm2bn(const float* __restrict__ src,
                                                 const float* __restrict__ res,
                                                 float* __restrict__ xout,
                                                 const float* __restrict__ st,
                                                 const float* __restrict__ g,
                                                 const float* __restrict__ b,
                                                 const short* __restrict__ Wt0,
                                                 const short* __restrict__ Wt1,
                                                 const float* __restrict__ bias0,
                                                 const float* __restrict__ bias1,
                                                 void* __restrict__ out0,
                                                 void* __restrict__ out1, int nRows) {
    __shared__ short As[128 * 136];
    __shared__ short Bs[128 * 136];
    __shared__ float scsh[256];
    const float invn = 1.f / NN;
    if (threadIdx.x < 128) {
        int c = threadIdx.x;
        float s0v = 0.f, s1v = 0.f;
#pragma unroll 8
        for (int k2 = 0; k2 < STS; ++k2) {
            s0v += st[k2 * 256 + c];
            s1v += st[k2 * 256 + 128 + c];
        }
        float mean = s0v * invn;
        float var = fmaxf(s1v * invn - mean * mean, 0.f);
        float s = g[c] * rsqrtf(var + EPSB);
        scsh[c] = s;
        scsh[128 + c] = b[c] - mean * s;
    }
    {
        const int4* Wt4 = (const int4*)Wt0;
        for (int idx = threadIdx.x; idx < 2048; idx += 256) {
            int row = idx >> 4, c8 = idx & 15;
            *(int4*)&Bs[row * 136 + c8 * 8] = Wt4[idx];
        }
    }
    __syncthreads();  // scsh ready
    int r0 = blockIdx.x * 128;
    int rows = nRows - r0; if (rows > 128) rows = 128;
    for (int idx = threadIdx.x; idx < 2048; idx += 256) {
        int r = idx >> 4, c8 = idx & 15;
        short4 sa = {0, 0, 0, 0}, sb = {0, 0, 0, 0};
        if (r < rows) {
            size_t base = (size_t)(r0 + r) * 128 + c8 * 8;
            float4 v0, v1;
            if (SRC16) {
                union { float4 f4; __half h[8]; } u;
                u.f4 = *(const float4*)&((const __half*)src)[base];
                v0 = make_float4(__half2float(u.h[0]), __half2float(u.h[1]),
                                 __half2float(u.h[2]), __half2float(u.h[3]));
                v1 = make_float4(__half2float(u.h[4]), __half2float(u.h[5]),
                                 __half2float(u.h[6]), __half2float(u.h[7]));
            } else {
                v0 = *(const float4*)&src[base];
                v1 = *(const float4*)&src[base + 4];
            }
            int c = c8 * 8;
            v0.x = fmaxf(v0.x * scsh[c + 0] + scsh[128 + c + 0], 0.f);
            v0.y = fmaxf(v0.y * scsh[c + 1] + scsh[128 + c + 1], 0.f);
            v0.z = fmaxf(v0.z * scsh[c + 2] + scsh[128 + c + 2], 0.f);
            v0.w = fmaxf(v0.w * scsh[c + 3] + scsh[128 + c + 3], 0.f);
            v1.x = fmaxf(v1.x * scsh[c + 4] + scsh[128 + c + 4], 0.f);
            v1.y = fmaxf(v1.y * scsh[c + 5] + scsh[128 + c + 5], 0.f);
            v1.z = fmaxf(v1.z * scsh[c + 6] + scsh[128 + c + 6], 0.f);
            v1.w = fmaxf(v1.w * scsh[c + 7] + scsh[128 + c + 7], 0.f);
            if (RES) {
                float4 rr0 = *(const float4*)&res[base];
                float4 rr1 = *(const float4*)&res[base + 4];
                v0.x += rr0.x; v0.y += rr0.y; v0.z += rr0.z; v0.w += rr0.w;
                v1.x += rr1.x; v1.y += rr1.y; v1.z += rr1.z; v1.w += rr1.w;
            }
            if (XOUT) {
                *(float4*)&xout[base] = v0;
                *(float4*)&xout[base + 4] = v1;
            }
            sa.x = f2bf(v0.x); sa.y = f2bf(v0.y); sa.z = f2bf(v0.z); sa.w = f2bf(v0.w);
            sb.x = f2bf(v1.x); sb.y = f2bf(v1.y); sb.z = f2bf(v1.z); sb.w = f2bf(v1.w);
        }
        *(short4*)&As[r * 136 + c8 * 8] = sa;
        *(short4*)&As[r * 136 + c8 * 8 + 4] = sb;
    }
    __syncthreads();
    int lane = threadIdx.x & 63, wave = threadIdx.x >> 6;
    int n16 = lane & 15, quad = lane >> 4;
    bf16x8 af[2][4];
#pragma unroll
    for (int rt = 0; rt < 2; ++rt)
#pragma unroll
        for (int kc = 0; kc < 4; ++kc)
            af[rt][kc] = *(const bf16x8*)&As[(wave * 32 + rt * 16 + n16) * 136 + kc * 32 + quad * 8];

    f32x4 acc[2][8];
#pragma unroll
    for (int rt = 0; rt < 2; ++rt)
#pragma unroll
        for (int ct = 0; ct < 8; ++ct) acc[rt][ct] = (f32x4){0.f, 0.f, 0.f, 0.f};
#pragma unroll
    for (int ct = 0; ct < 8; ++ct)
#pragma unroll
        for (int kc = 0; kc < 4; ++kc) {
            bf16x8 bf = *(const bf16x8*)&Bs[(ct * 16 + n16) * 136 + kc * 32 + quad * 8];
            acc[0][ct] = __builtin_amdgcn_mfma_f32_16x16x32_bf16(af[0][kc], bf, acc[0][ct], 0, 0, 0);
            acc[1][ct] = __builtin_amdgcn_mfma_f32_16x16x32_bf16(af[1][kc], bf, acc[1][ct], 0, 0, 0);
        }
#pragma unroll
    for (int ct = 0; ct < 8; ++ct) {
        int colI = ct * 16 + n16;
        float bv = bias0[colI];
#pragma unroll
        for (int rt = 0; rt < 2; ++rt)
#pragma unroll
            for (int reg = 0; reg < 4; ++reg) {
                int r = wave * 32 + rt * 16 + quad * 4 + reg;  // C/D: col=lane&15, row=quad*4+reg
                if (r < rows) {
                    float v = acc[rt][ct][reg] + bv;
                    if (OUTH0) ((__half*)out0)[(size_t)(r0 + r) * 128 + colI] = __float2half(v);
                    else       ((float*)out0)[(size_t)(r0 + r) * 128 + colI] = v;
                }
            }
    }
    __syncthreads();
    {
        const int4* Wt4 = (const int4*)Wt1;
        for (int idx = threadIdx.x; idx < 2048; idx += 256) {
            int row = idx >> 4, c8 = idx & 15;
            *(int4*)&Bs[row * 136 + c8 * 8] = Wt4[idx];
        }
    }
    __syncthreads();
#pragma unroll
    for (int rt = 0; rt < 2; ++rt)
#pragma unroll
        for (int ct = 0; ct < 8; ++ct) acc[rt][ct] = (f32x4){0.f, 0.f, 0.f, 0.f};
#pragma unroll
    for (int ct = 0; ct < 8; ++ct)
#pragma unroll
        for (int kc = 0; kc < 4; ++kc) {
            bf16x8 bf = *(const bf16x8*)&Bs[(ct * 16 + n16) * 136 + kc * 32 + quad * 8];
            acc[0][ct] = __builtin_amdgcn_mfma_f32_16x16x32_bf16(af[0][kc], bf, acc[0][ct], 0, 0, 0);
            acc[1][ct] = __builtin_amdgcn_mfma_f32_16x16x32_bf16(af[1][kc], bf, acc[1][ct], 0, 0, 0);
        }
#pragma unroll
    for (int ct = 0; ct < 8; ++ct) {
        int colI = ct * 16 + n16;
        float bv = bias1[colI];
#pragma unroll
        for (int rt = 0; rt < 2; ++rt)
#pragma unroll
            for (int reg = 0; reg < 4; ++reg) {
                int r = wave * 32 + rt * 16 + quad * 4 + reg;
                if (r < rows) {
                    float v = acc[rt][ct][reg] + bv;
                    if (OUTH1) ((__half*)out1)[(size_t)(r0 + r) * 128 + colI] = __float2half(v);
                    else       ((float*)out1)[(size_t)(r0 + r) * 128 + colI] = v;
                }
            }
    }
}

// ------- QUAD-fused MFMA GEMM (Q/K/V/S), 128-row tile; src fp16; KV interleaved ----
// Outputs: Q -> oq (stride 128); K -> okv[node*256 + c]; V -> okv[node*256+128+c];
// S -> os (stride 128).
__global__ __launch_bounds__(256) void k_gemm4bn(const __half* __restrict__ src,
                                                 const float* __restrict__ res,
                                                 float* __restrict__ xout,
                                                 const float* __restrict__ st,
                                                 const float* __restrict__ g,
                                                 const float* __restrict__ b,
                                                 const short* __restrict__ Wt,
                                                 const float* __restrict__ bq,
                                                 const float* __restrict__ bk,
                                                 const float* __restrict__ bv,
                                                 const float* __restrict__ bs,
                                                 __half* __restrict__ oq,
                                                 __half* __restrict__ okv,
                                                 __half* __restrict__ os, int nRows) {
    __shared__ short As[128 * 136];
    __shared__ short Bs[128 * 136];
    __shared__ float scsh[256];
    const float invn = 1.f / NN;
    if (threadIdx.x < 128) {
        int c = threadIdx.x;
        float s0v = 0.f, s1v = 0.f;
#pragma unroll 8
        for (int k2 = 0; k2 < STS; ++k2) {
            s0v += st[k2 * 256 + c];
            s1v += st[k2 * 256 + 128 + c];
        }
        float mean = s0v * invn;
        float var = fmaxf(s1v * invn - mean * mean, 0.f);
        float s = g[c] * rsqrtf(var + EPSB);
        scsh[c] = s;
        scsh[128 + c] = b[c] - mean * s;
    }
    __syncthreads();  // scsh ready
    int r0 = blockIdx.x * 128;
    int rows = nRows - r0; if (rows > 128) rows = 128;
    for (int idx = threadIdx.x; idx < 2048; idx += 256) {
        int r = idx >> 4, c8 = idx & 15;
        short4 sa = {0, 0, 0, 0}, sb = {0, 0, 0, 0};
        if (r < rows) {
            size_t base = (size_t)(r0 + r) * 128 + c8 * 8;
            union { float4 f4; __half h[8]; } u;
            u.f4 = *(const float4*)&src[base];
            float4 v0 = make_float4(__half2float(u.h[0]), __half2float(u.h[1]),
                                    __half2float(u.h[2]), __half2float(u.h[3]));
            float4 v1 = make_float4(__half2float(u.h[4]), __half2float(u.h[5]),
                                    __half2float(u.h[6]), __half2float(u.h[7]));
            int c = c8 * 8;
            v0.x = fmaxf(v0.x * scsh[c + 0] + scsh[128 + c + 0], 0.f);
            v0.y = fmaxf(v0.y * scsh[c + 1] + scsh[128 + c + 1], 0.f);
            v0.z = fmaxf(v0.z * scsh[c + 2] + scsh[128 + c + 2], 0.f);
            v0.w = fmaxf(v0.w * scsh[c + 3] + scsh[128 + c + 3], 0.f);
            v1.x = fmaxf(v1.x * scsh[c + 4] + scsh[128 + c + 4], 0.f);
            v1.y = fmaxf(v1.y * scsh[c + 5] + scsh[128 + c + 5], 0.f);
            v1.z = fmaxf(v1.z * scsh[c + 6] + scsh[128 + c + 6], 0.f);
            v1.w = fmaxf(v1.w * scsh[c + 7] + scsh[128 + c + 7], 0.f);
            float4 rr0 = *(const float4*)&res[base];
            float4 rr1 = *(const float4*)&res[base + 4];
            v0.x += rr0.x; v0.y += rr0.y; v0.z += rr0.z; v0.w += rr0.w;
            v1.x += rr1.x; v1.y += rr1.y; v1.z += rr1.z; v1.w += rr1.w;
            *(float4*)&xout[base] = v0;
            *(float4*)&xout[base + 4] = v1;
            sa.x = f2bf(v0.x); sa.y = f2bf(v0.y); sa.z = f2bf(v0.z); sa.w = f2bf(v0.w);
            sb.x = f2bf(v1.x); sb.y = f2bf(v1.y); sb.z = f2bf(v1.z); sb.w = f2bf(v1.w);
        }
        *(short4*)&As[r * 136 + c8 * 8] = sa;
        *(short4*)&As[r * 136 + c8 * 8 + 4] = sb;
    }
    int lane = threadIdx.x & 63, wave = threadIdx.x >> 6;
    int n16 = lane & 15, quad = lane >> 4;
    bf16x8 af[2][4];
    bool afLoaded = false;
    for (int m = 0; m < 4; ++m) {
        {
            const int4* Wt4 = (const int4*)(Wt + (size_t)m * 16384);
            for (int idx = threadIdx.x; idx < 2048; idx += 256) {
                int row = idx >> 4, c8 = idx & 15;
                *(int4*)&Bs[row * 136 + c8 * 8] = Wt4[idx];
            }
        }
        __syncthreads();
        if (!afLoaded) {
            afLoaded = true;
#pragma unroll
            for (int rt = 0; rt < 2; ++rt)
#pragma unroll
                for (int kc = 0; kc < 4; ++kc)
                    af[rt][kc] = *(const bf16x8*)&As[(wave * 32 + rt * 16 + n16) * 136 + kc * 32 + quad * 8];
        }
        f32x4 acc[2][8];
#pragma unroll
        for (int rt = 0; rt < 2; ++rt)
#pragma unroll
            for (int ct = 0; ct < 8; ++ct) acc[rt][ct] = (f32x4){0.f, 0.f, 0.f, 0.f};
#pragma unroll
        for (int ct = 0; ct < 8; ++ct)
#pragma unroll
            for (int kc = 0; kc < 4; ++kc) {
                bf16x8 bf = *(const bf16x8*)&Bs[(ct * 16 + n16) * 136 + kc * 32 + quad * 8];
                acc[0][ct] = __builtin_amdgcn_mfma_f32_16x16x32_bf16(af[0][kc], bf, acc[0][ct], 0, 0, 0);
                acc[1][ct] = __builtin_amdgcn_mfma_f32_16x16x32_bf16(af[1][kc], bf, acc[1][ct], 0, 0, 0);
            }
        __half* om; int strd, off;
        const float* bm;
        if (m == 0)      { om = oq;  strd = 128; off = 0;   bm = bq; }
        else if (m == 1) { om = okv; strd = 256; off = 0;   bm = bk; }
        else if (m == 2) { om = okv; strd = 256; off = 128; bm = bv; }
        else             { om = os;  strd = 128; off = 0;   bm = bs; }
#pragma unroll
        for (int ct = 0; ct < 8; ++ct) {
            int colI = ct * 16 + n16;
            float bv2 = bm[colI];
#pragma unroll
            for (int rt = 0; rt < 2; ++rt)
#pragma unroll
                for (int reg = 0; reg < 4; ++reg) {
                    int r = wave * 32 + rt * 16 + quad * 4 + reg;
                    if (r < rows)
                        om[(size_t)(r0 + r) * strd + off + colI] = __float2half(acc[rt][ct][reg] + bv2);
                }
        }
        if (m < 3) __syncthreads();  // protect Bs before next stage
    }
}

// ---- FUSED GAT edge pass: quarter-wave per edge (r4-proven structure), fp16 out ----
__global__ __launch_bounds__(256) void k_gat_aggr(const __half* __restrict__ xl,
                                                  const __half* __restrict__ xr,
                                                  const float* __restrict__ att,
                                                  const float* __restrict__ gbias_l,
                                                  const int* __restrict__ rp,
                                                  const int* __restrict__ esrc,
                                                  __half* __restrict__ out) {
    int lane = threadIdx.x & 63;
    int node = blockIdx.x * 4 + (threadIdx.x >> 6);
    if (node >= NN) return;
    int q = lane >> 4;      // edge strand 0..3
    int l16 = lane & 15;
    int c8 = l16 * 8;
    float4 xrr = *(const float4*)&xr[(unsigned)node * 128u + c8];
    hv2 xrh[4] = {*(hv2*)&xrr.x, *(hv2*)&xrr.y, *(hv2*)&xrr.z, *(hv2*)&xrr.w};
    float4 atA = *(const float4*)&att[c8];
    float4 atB = *(const float4*)&att[c8 + 4];
    hv2 ath[4] = {{(_Float16)atA.x, (_Float16)atA.y}, {(_Float16)atA.z, (_Float16)atA.w},
                  {(_Float16)atB.x, (_Float16)atB.y}, {(_Float16)atB.z, (_Float16)atB.w}};
    const hv2 hz = {(_Float16)0.f, (_Float16)0.f};
    const hv2 hs = {(_Float16)LSLOPE, (_Float16)LSLOPE};
    int s0 = rp[node];
    int T = rp[node + 1] - s0 + 1;  // logical edge T-1 is the self loop
    float a[8] = {0.f, 0.f, 0.f, 0.f, 0.f, 0.f, 0.f, 0.f};
    float l = 0.f;
    auto body = [&](int j) {
        bool self = (j == T - 1);
        int srcn = self ? node : esrc[s0 + j];
        float4 raw = *(const float4*)&xl[(unsigned)srcn * 128u + c8];
        hv2 f[4] = {*(hv2*)&raw.x, *(hv2*)&raw.y, *(hv2*)&raw.z, *(hv2*)&raw.w};
        float p = 0.f;
#pragma unroll
        for (int k = 0; k < 4; ++k) {
            hv2 e = f[k] + xrh[k];
            hv2 lk = __builtin_elementwise_max(e, hz) + hs * __builtin_elementwise_min(e, hz);
            p = fdot2(lk, ath[k], p);
        }
        p += __shfl_xor(p, 1); p += __shfl_xor(p, 2);
        float w = __expf(p);
#pragma unroll
        for (int k = 0; k < 4; ++k) {
            a[2 * k] += w * (float)f[k].x;
            a[2 * k + 1] += w * (float)f[k].y;
        }
        l += w;
    };
    int j = q;
    for (; j + 12 < T; j += 16) { body(j); body(j + 4); body(j + 8); body(j + 12); }
    for (; j + 4 < T; j += 8) { body(j); body(j + 4); }
    for (; j < T; j += 4) body(j);
#pragma unroll
    for (int k = 0; k < 8; ++k) { a[k] += __shfl_xor(a[k], 16); a[k] += __shfl_xor(a[k], 32); }
    l += __shfl_xor(l, 16); l += __shfl_xor(l, 32);
    if (q == 0) {
        float inv = 1.f / (l + 1e-16f);
        float4 gb0 = *(const float4*)&gbias_l[c8];
        float4 gb1 = *(const float4*)&gbias_l[c8 + 4];
        union { float4 f4; __half h[8]; } u;
        u.h[0] = __float2half(a[0] * inv + gb0.x); u.h[1] = __float2half(a[1] * inv + gb0.y);
        u.h[2] = __float2half(a[2] * inv + gb0.z); u.h[3] = __float2half(a[3] * inv + gb0.w);
        u.h[4] = __float2half(a[4] * inv + gb1.x); u.h[5] = __float2half(a[5] * inv + gb1.y);
        u.h[6] = __float2half(a[6] * inv + gb1.z); u.h[7] = __float2half(a[7] * inv + gb1.w);
        *(float4*)&out[(unsigned)node * 128u + c8] = u.f4;
    }
}

// ---- FUSED Transformer edge pass: quarter-wave per edge, INTERLEAVED KV gather -----
__global__ __launch_bounds__(256) void k_trans_aggr(const __half* __restrict__ qh,
                                                    const __half* __restrict__ kv,
                                                    const __half* __restrict__ sT,
                                                    const int* __restrict__ rp,
                                                    const int* __restrict__ esrc,
                                                    __half* __restrict__ out) {
    int lane = threadIdx.x & 63;
    int node = blockIdx.x * 4 + (threadIdx.x >> 6);
    if (node >= NN) return;
    int q = lane >> 4;
    int l16 = lane & 15;
    int c8 = l16 * 8;
    float4 qr = *(const float4*)&qh[(unsigned)node * 128u + c8];
    const hv2 hinv = {(_Float16)INV_SQRT_C, (_Float16)INV_SQRT_C};
    hv2 qv[4] = {(*(hv2*)&qr.x) * hinv, (*(hv2*)&qr.y) * hinv,
                 (*(hv2*)&qr.z) * hinv, (*(hv2*)&qr.w) * hinv};
    int s0 = rp[node];
    int T = rp[node + 1] - s0;
    float a[8] = {0.f, 0.f, 0.f, 0.f, 0.f, 0.f, 0.f, 0.f};
    float l = 0.f;
    auto body = [&](int j) {
        int srcn = esrc[s0 + j];
        const __half* kvp = &kv[(unsigned)srcn * 256u + c8];
        float4 kraw = *(const float4*)kvp;          // K slice
        float4 vraw = *(const float4*)(kvp + 128);  // V slice (same 256B node block)
        hv2 kvv[4] = {*(hv2*)&kraw.x, *(hv2*)&kraw.y, *(hv2*)&kraw.z, *(hv2*)&kraw.w};
        float p = 0.f;
#pragma unroll
        for (int k = 0; k < 4; ++k) p = fdot2(kvv[k], qv[k], p);
        p += __shfl_xor(p, 1); p += __shfl_xor(p, 2);
        float w = __expf(p);
        hv2 vvv[4] = {*(hv2*)&vraw.x, *(hv2*)&vraw.y, *(hv2*)&vraw.z, *(hv2*)&vraw.w};
#pragma unroll
        for (int k = 0; k < 4; ++k) {
            a[2 * k] += w * (float)vvv[k].x;
            a[2 * k + 1] += w * (float)vvv[k].y;
        }
        l += w;
    };
    int j = q;
    for (; j + 12 < T; j += 16) { body(j); body(j + 4); body(j + 8); body(j + 12); }
    for (; j + 4 < T; j += 8) { body(j); body(j + 4); }
    for (; j < T; j += 4) body(j);
#pragma unroll
    for (int k = 0; k < 8; ++k) { a[k] += __shfl_xor(a[k], 16); a[k] += __shfl_xor(a[k], 32); }
    l += __shfl_xor(l, 16); l += __shfl_xor(l, 32);
    if (q == 0) {
        float inv = 1.f / (l + 1e-16f);
        float4 straw = *(const float4*)&sT[(unsigned)node * 128u + c8];
        hv2 st[4] = {*(hv2*)&straw.x, *(hv2*)&straw.y, *(hv2*)&straw.z, *(hv2*)&straw.w};
        union { float4 f4; __half h[8]; } u;
        u.h[0] = __float2half(a[0] * inv + (float)st[0].x);
        u.h[1] = __float2half(a[1] * inv + (float)st[0].y);
        u.h[2] = __float2half(a[2] * inv + (float)st[1].x);
        u.h[3] = __float2half(a[3] * inv + (float)st[1].y);
        u.h[4] = __float2half(a[4] * inv + (float)st[2].x);
        u.h[5] = __float2half(a[5] * inv + (float)st[2].y);
        u.h[6] = __float2half(a[6] * inv + (float)st[3].x);
        u.h[7] = __float2half(a[7] * inv + (float)st[3].y);
        *(float4*)&out[(unsigned)node * 128u + c8] = u.f4;
    }
}

// ---- pooling phase 1 WITH FUSED final BN: v = bn(src fp16) + res, per-graph sum/max -
__global__ __launch_bounds__(256) void k_pool_part(const __half* __restrict__ src,
                                                   const float* __restrict__ res,
                                                   const float* __restrict__ st,
                                                   const float* __restrict__ g,
                                                   const float* __restrict__ b,
                                                   const int* __restrict__ batch,
                                                   float* __restrict__ psum,
                                                   unsigned* __restrict__ pmax) {
    __shared__ int bs[64];
    __shared__ float sc_sh[128], sh_sh[128];
    int r0 = blockIdx.x * 64;
    if (threadIdx.x < 64) {
        int r = r0 + threadIdx.x;
        bs[threadIdx.x] = (r < NN) ? batch[r] : -1;
    }
    const float invn = 1.f / NN;
    if (threadIdx.x < 128) {
        int c2 = threadIdx.x;
        float s0v = 0.f, s1v = 0.f;
#pragma unroll 8
        for (int k2 = 0; k2 < STS; ++k2) {
            s0v += st[k2 * 256 + c2];
            s1v += st[k2 * 256 + 128 + c2];
        }
        float mean = s0v * invn;
        float var = fmaxf(s1v * invn - mean * mean, 0.f);
        float scv = g[c2] * rsqrtf(var + EPSB);
        sc_sh[c2] = scv;
        sh_sh[c2] = b[c2] - mean * scv;
    }
    __syncthreads();
    int c = threadIdx.x & 127;
    int sub = threadIdx.x >> 7;
    float scv = sc_sh[c];
    float shv = sh_sh[c];
    int curg = -1;
    float s = 0.f, fmx = -INFINITY;
    for (int i = sub; i < 64; i += 2) {
        int r = r0 + i;
        if (r >= NN) break;
        int gr = bs[i];
        if (gr != curg) {
            if (curg >= 0) {
                atomicAdd(&psum[curg * 128 + c], s);
                atomicMax(&pmax[curg * 128 + c], fenc(fmx));
            }
            curg = gr; s = 0.f; fmx = -INFINITY;
        }
        float v = __half2float(src[(size_t)r * 128 + c]) * scv + shv + res[(size_t)r * 128 + c];
        s += v; fmx = fmaxf(fmx, v);
    }
    if (curg >= 0) {
        atomicAdd(&psum[curg * 128 + c], s);
        atomicMax(&pmax[curg * 128 + c], fenc(fmx));
    }
}

// ---------------- pooling finalize + head1 GEMM + fused stats6 ----------------
__global__ __launch_bounds__(128) void k_pool_head1(const float* __restrict__ psum,
                                                    const unsigned* __restrict__ pmax,
                                                    const int* __restrict__ batch,
                                                    const float* __restrict__ W,
                                                    const float* __restrict__ b,
                                                    float* __restrict__ t1,
                                                    float* __restrict__ st6) {
    __shared__ float hr[256];
    __shared__ int se[2];
    int g = blockIdx.x;
    int t = threadIdx.x;
    if (t == 0) {
        int lo = 0, hi = NN;
        while (lo < hi) { int mid = (lo + hi) >> 1; if (batch[mid] < g) lo = mid + 1; else hi = mid; }
        se[0] = lo;
        hi = NN;
        while (lo < hi) { int mid = (lo + hi) >> 1; if (batch[mid] < g + 1) lo = mid + 1; else hi = mid; }
        se[1] = lo;
    }
    __syncthreads();
    int cnt = se[1] - se[0];
    float xm = psum[g * 128 + t] / fmaxf((float)cnt, 1.f);
    float xx = (cnt > 0) ? fdec(pmax[g * 128 + t]) : 0.f;
    hr[t] = xm;
    hr[128 + t] = xx;
    __syncthreads();
    float acc = b[t];
#pragma unroll 4
    for (int k = 0; k < 256; ++k) acc += hr[k] * W[k * 128 + t];
    t1[g * 128 + t] = acc;
    atomicAdd(&st6[t], acc);
    atomicAdd(&st6[128 + t], acc * acc);
}

__global__ __launch_bounds__(64) void k_head2(const float* __restrict__ t1,
                                              const float* __restrict__ st,
                                              const float* __restrict__ og,
                                              const float* __restrict__ obe,
                                              const float* __restrict__ W2,
                                              const float* __restrict__ b2,
                                              const float* __restrict__ W3,
                                              const float* __restrict__ b3,
                                              float* __restrict__ out) {
    __shared__ float v[128];
    int row = blockIdx.x, t = threadIdx.x;
    const float invn = 1.f / NG;
#pragma unroll
    for (int half = 0; half < 2; ++half) {
        int ch = t + half * 64;
        float mean = st[ch] * invn;
        float var = fmaxf(st[128 + ch] * invn - mean * mean, 0.f);
        float scv = og[ch] * rsqrtf(var + EPSB);
        float shv = obe[ch] - mean * scv;
        float a = t1[row * 128 + ch] * scv + shv;
        v[ch] = fmaxf(a, 0.f);
    }
    __syncthreads();
    float acc = b2[t];
#pragma unroll 4
    for (int k = 0; k < 128; ++k) acc += v[k] * W2[k * 64 + t];
    float p = fmaxf(acc, 0.f) * W3[t];
    p += __shfl_xor(p, 1); p += __shfl_xor(p, 2); p += __shfl_xor(p, 4);
    p += __shfl_xor(p, 8); p += __shfl_xor(p, 16); p += __shfl_xor(p, 32);
    if (t == 0) out[row] = p + b3[0];
}

// ---------------- launch ----------------
extern "C" void kernel_launch(void* const* d_in, const int* in_sizes, int n_in,
                              void* d_out, int out_size, void* d_ws, size_t ws_size,
                              hipStream_t stream) {
    const float* x_in   = (const float*)d_in[0];
    const int*   ei     = (const int*)d_in[1];
    const int*   batch  = (const int*)d_in[2];
    const float* emb_W  = (const float*)d_in[3];
    const float* emb_b  = (const float*)d_in[4];
    const float* emb_g  = (const float*)d_in[5];
    const float* emb_be = (const float*)d_in[6];
    const float* gWl    = (const float*)d_in[7];
    const float* gWr    = (const float*)d_in[8];
    const float* gbl    = (const float*)d_in[9];
    const float* gbr    = (const float*)d_in[10];
    const float* gatt   = (const float*)d_in[11];
    const float* gbias  = (const float*)d_in[12];
    const float* gg     = (const float*)d_in[13];
    const float* gbe    = (const float*)d_in[14];
    const float* tWq    = (const float*)d_in[15];
    const float* tWk    = (const float*)d_in[16];
    const float* tWv    = (const float*)d_in[17];
    const float* tWs    = (const float*)d_in[18];
    const float* tbq    = (const float*)d_in[19];
    const float* tbk    = (const float*)d_in[20];
    const float* tbv    = (const float*)d_in[21];
    const float* tbs    = (const float*)d_in[22];
    const float* tg     = (const float*)d_in[23];
    const float* tbe    = (const float*)d_in[24];
    const float* oW1    = (const float*)d_in[25];
    const float* ob1    = (const float*)d_in[26];
    const float* og     = (const float*)d_in[27];
    const float* obe    = (const float*)d_in[28];
    const float* oW2    = (const float*)d_in[29];
    const float* ob2    = (const float*)d_in[30];
    const float* oW3    = (const float*)d_in[31];
    const float* ob3    = (const float*)d_in[32];
    float* out = (float*)d_out;

    const size_t NDsz = (size_t)NN * 128;
    float* x     = (float*)d_ws;       // ping
    float* bA    = x + NDsz;           // pong
    float* bC    = bA + NDsz;          // aggr output (fp16 view; also emb-out staging)
    float* stats = bC + NDsz;          // 7 * 256 floats (only slot 6 live now)
    float* hpool = stats + 7 * 256;    // 256*256 (dead; layout preserved)
    float* t1    = hpool + 65536;      // 256*128
    float* scb   = t1 + 32768;         // hosts rank (NE ints) + multi-slot stats
    __half* xlh  = (__half*)(scb + (size_t)(NE + NN) * 4);  // xl / S-skip
    __half* xrh  = xlh + NDsz;         // xr / Q
    __half* vh   = xrh + NDsz;         // start of interleaved KV region (NN*256 halfs,
    __half* sh   = vh + NDsz;          //   spans old vh+sh)
    short* Wt    = (short*)(sh + NDsz);  // 12 * 128*128 bf16 transposed
    int* deg     = (int*)(Wt + 12 * 16384);
    int* rp      = deg + NN;
    int* cursor  = rp + NN + 1;        // kept (dead) to preserve proven layout
    int2* edg    = (int2*)(cursor + NN);  // NE+64 slots; used as int src-list
    int* bsum    = (int*)(edg + NE + 64);
    int* boff    = bsum + 256;
    float* psum  = (float*)(boff + 256);            // NG*128
    unsigned* pmax = (unsigned*)(psum + NG * 128);  // NG*128
    int* rank    = (int*)scb;          // aliases scb, uses [0, NE)
    int* esrc    = (int*)edg;          // src-only edge list (padded past NE)
    // multi-slot stats: 6 regions x STS x 256 floats, in the slack after rank
    float* stms  = scb + NE;
    __half* bCh  = (__half*)bC;        // fp16 view of the aggregator buffer
    __half* kvh  = vh;                 // interleaved KV (node-major, 256 halfs/node)

    hipMemsetAsync(deg, 0, NN * sizeof(int), stream);
    hipMemsetAsync(stats + 6 * 256, 0, 256 * sizeof(float), stream);      // stats6
    hipMemsetAsync(stms, 0, 6 * STS * 256 * sizeof(float), stream);       // spread stats
    hipMemsetAsync(psum, 0, NG * 128 * 2 * sizeof(float), stream);        // psum + pmax

    const int gGemm = (NN + 127) / 128;  // 128-row tiles (r6-proven)
    const int gStat = (NN + 127) / 128;
    const int gNode = (NN + 3) / 4;
    const int gPool = (NN + 63) / 64;
    const int REG = STS * 256;  // stats region stride

    // degree histogram (isolated, 8 atomic strands/thread for MLP)
    k_deg<<<GD, 256, 0, stream>>>(ei, deg, rank);
    // weight prep + embedding GEMM (fp16 out into idle bC region)
    k_init<<<12 + GE, 256, 0, stream>>>(gWl, gWr, tWq, tWk, tWv, tWs,
                                        Wt, x_in, emb_W, emb_b, bCh, stms + 0 * REG);

    // CSR by destination (rank-based; k_fill is atomic-free)
    k_scan1<<<NB, 256, 0, stream>>>(deg, bsum);
    k_scan2<<<1, 256, 0, stream>>>(bsum, boff, rp);
    k_scan3<<<NB, 256, 0, stream>>>(deg, boff, rp);
    k_fill<<<GQ, 256, 0, stream>>>(ei, rp, rank, esrc);

    // ping-pong feature buffers: residual source alternates x <-> bA
    k_gemm2bn<1, 1, 1, 0, 1><<<gGemm, 256, 0, stream>>>((const float*)bCh, nullptr, x, stms + 0 * REG, emb_g, emb_be,
                                                        Wt + (size_t)0 * 16384, Wt + (size_t)4 * 16384,
                                                        gbl + 0 * 128, gbr + 0 * 128, xlh, xrh, NN);
    k_gat_aggr<<<gNode, 256, 0, stream>>>(xlh, xrh, gatt + 0 * 128, gbias + 0 * 128, rp, esrc, bCh);
    k_stats<<<gStat, 256, 0, stream>>>(bCh, NN, stms + 1 * REG);
    k_gemm2bn<1, 1, 1, 1, 1><<<gGemm, 256, 0, stream>>>((const float*)bCh, x, bA, stms + 1 * REG, gg + 0 * 128, gbe + 0 * 128,
                                                        Wt + (size_t)1 * 16384, Wt + (size_t)5 * 16384,
                                                        gbl + 1 * 128, gbr + 1 * 128, xlh, xrh, NN);
    k_gat_aggr<<<gNode, 256, 0, stream>>>(xlh, xrh, gatt + 1 * 128, gbias + 1 * 128, rp, esrc, bCh);
    k_stats<<<gStat, 256, 0, stream>>>(bCh, NN, stms + 2 * REG);
    k_gemm2bn<1, 1, 1, 1, 1><<<gGemm, 256, 0, stream>>>((const float*)bCh, bA, x, stms + 2 * REG, gg + 1 * 128, gbe + 1 * 128,
                                                        Wt + (size_t)2 * 16384, Wt + (size_t)6 * 16384,
                                                        gbl + 2 * 128, gbr + 2 * 128, xlh, xrh, NN);
    k_gat_aggr<<<gNode, 256, 0, stream>>>(xlh, xrh, gatt + 2 * 128, gbias + 2 * 128, rp, esrc, bCh);
    k_stats<<<gStat, 256, 0, stream>>>(bCh, NN, stms + 3 * REG);
    k_gemm2bn<1, 1, 1, 1, 1><<<gGemm, 256, 0, stream>>>((const float*)bCh, x, bA, stms + 3 * REG, gg + 2 * 128, gbe + 2 * 128,
                                                        Wt + (size_t)3 * 16384, Wt + (size_t)7 * 16384,
                                                        gbl + 3 * 128, gbr + 3 * 128, xlh, xrh, NN);
    k_gat_aggr<<<gNode, 256, 0, stream>>>(xlh, xrh, gatt + 3 * 128, gbias + 3 * 128, rp, esrc, bCh);
    k_stats<<<gStat, 256, 0, stream>>>(bCh, NN, stms + 4 * REG);

    // TransformerConv: ONE quad GEMM for Q / interleaved-KV / S (A staged once)
    k_gemm4bn<<<gGemm, 256, 0, stream>>>(bCh, bA, x, stms + 4 * REG, gg + 3 * 128, gbe + 3 * 128,
                                         Wt + (size_t)8 * 16384, tbq, tbk, tbv, tbs,
                                         xrh, kvh, xlh, NN);  // Q, KV, S
    k_trans_aggr<<<gNode, 256, 0, stream>>>(xrh, kvh, xlh, rp, esrc, bCh);
    k_stats<<<gStat, 256, 0, stream>>>(bCh, NN, stms + 5 * REG);

    // pooling (with fused final BN: v = bn(bC fp16) + x) + head
    k_pool_part<<<gPool, 256, 0, stream>>>(bCh, x, stms + 5 * REG, tg, tbe, batch, psum, pmax);
    k_pool_head1<<<NG, 128, 0, stream>>>(psum, pmax, batch, oW1, ob1, t1, stats + 6 * 256);
    k_head2<<<NG, 64, 0, stream>>>(t1, stats + 6 * 256, og, obe, oW2, ob2, oW3, ob3, out);
}

// Round 11
// 773.365 us; speedup vs baseline: 1.0250x; 1.0250x over previous
//
#include <hip/hip_runtime.h>
#include <hip/hip_fp16.h>

// ---------------- constants ----------------
namespace {
constexpr int NN = 50000;   // nodes
constexpr int NE = 800000;  // edges
constexpr int NG = 256;     // graphs
constexpr int NF = 34;      // in features
constexpr int NL = 4;       // GAT layers
constexpr int NB = (NN + 255) / 256;  // scan blocks = 196
constexpr int STS = 32;     // stats slot spread
constexpr int GQ = ((NE + 3) / 4 + 255) / 256;   // 782 fill blocks
constexpr int GD = ((NE + 7) / 8 + 255) / 256;   // 391 deg blocks (8 strands)
constexpr int GE = (NN + 63) / 64;               // 782 emb blocks
}
#define EPSB 1e-5f
#define LSLOPE 0.2f
#define INV_SQRT_C 0.17677669529663687f  // 1/sqrt(32)

typedef short bf16x8 __attribute__((ext_vector_type(8)));
typedef float f32x4 __attribute__((ext_vector_type(4)));
typedef _Float16 hv2 __attribute__((ext_vector_type(2)));

static __device__ __forceinline__ short f2bf(float f) {
    unsigned int u = __float_as_uint(f);
    u = (u + 0x7fff + ((u >> 16) & 1)) >> 16;  // RNE
    return (short)u;
}
// order-preserving float<->uint for atomicMax; all encodings > 0, so memset-0 = -inf
static __device__ __forceinline__ unsigned fenc(float x) {
    unsigned u = __float_as_uint(x);
    return (u & 0x80000000u) ? ~u : (u | 0x80000000u);
}
static __device__ __forceinline__ float fdec(unsigned u) {
    return __uint_as_float((u & 0x80000000u) ? (u ^ 0x80000000u) : ~u);
}
// v_dot2_f32_f16: c += a.x*b.x + a.y*b.y (fp32 accumulate)
static __device__ __forceinline__ float fdot2(hv2 a, hv2 b, float c) {
    return __builtin_amdgcn_fdot2(a, b, c, false);
}

// ---------------- MERGED front-end: deg (8-strand atomics) + prep + emb GEMM -------
// blocks [0,GD): degree; [GD,GD+12): weight transpose; [GD+12, GD+12+GE): emb GEMM
__global__ __launch_bounds__(256) void k_init(const int* __restrict__ ei,
                                              int* __restrict__ deg,
                                              int* __restrict__ rank,
                                              const float* __restrict__ gWl,
                                              const float* __restrict__ gWr,
                                              const float* __restrict__ tWq,
                                              const float* __restrict__ tWk,
                                              const float* __restrict__ tWv,
                                              const float* __restrict__ tWs,
                                              short* __restrict__ Wt,
                                              const float* __restrict__ A,
                                              const float* __restrict__ W,
                                              const float* __restrict__ bias,
                                              __half* __restrict__ outEmb,
                                              float* __restrict__ stms) {
    __shared__ float As[64 * NF];
    __shared__ float sred[256];
    int blk = blockIdx.x;
    if (blk < GD) {  // ---- degree count, 8 disjoint strands/thread
        int tid = blk * 256 + threadIdx.x;
        const int S = (NE + 7) / 8;
        if (tid >= S) return;
#pragma unroll
        for (int k = 0; k < 8; ++k) {
            int e = tid + k * S;
            if (e < NE) rank[e] = atomicAdd(&deg[ei[NE + e]], 1);
        }
        return;
    }
    blk -= GD;
    if (blk < 12) {  // ---- weight prep: (128,128) fp32 -> transposed bf16
        const float* src;
        if (blk < 4) src = gWl + blk * 16384;
        else if (blk < 8) src = gWr + (blk - 4) * 16384;
        else if (blk == 8) src = tWq;
        else if (blk == 9) src = tWk;
        else if (blk == 10) src = tWv;
        else src = tWs;
        short* d = Wt + blk * 16384;
        for (int i = threadIdx.x; i < 16384; i += 256) {
            int n = i >> 7, k = i & 127;
            d[i] = f2bf(src[k * 128 + n]);  // Wt[n][k] = W[k][n]
        }
        return;
    }
    blk -= 12;
    // ---- embedding GEMM (n,34)@(34,128)+bias, fp16 out, fused col-stats
    int r0 = blk * 64;
    int rows = NN - r0; if (rows > 64) rows = 64;
    int total = rows * NF;
    for (int idx = threadIdx.x; idx < 64 * NF; idx += 256)
        As[idx] = (idx < total) ? A[(size_t)r0 * NF + idx] : 0.f;
    sred[threadIdx.x] = 0.f;
    __syncthreads();
    int tx = threadIdx.x & 31, ty = threadIdx.x >> 5;
    const float4* W4 = (const float4*)W;
    float acc[8][4];
#pragma unroll
    for (int j = 0; j < 8; ++j)
#pragma unroll
        for (int i = 0; i < 4; ++i) acc[j][i] = 0.f;
#pragma unroll 2
    for (int k = 0; k < NF; ++k) {
        float4 w = W4[k * 32 + tx];
#pragma unroll
        for (int j = 0; j < 8; ++j) {
            float a = As[(ty * 8 + j) * NF + k];
            acc[j][0] += a * w.x; acc[j][1] += a * w.y;
            acc[j][2] += a * w.z; acc[j][3] += a * w.w;
        }
    }
    float4 b = ((const float4*)bias)[tx];
    float s[4] = {0.f, 0.f, 0.f, 0.f}, ss[4] = {0.f, 0.f, 0.f, 0.f};
#pragma unroll
    for (int j = 0; j < 8; ++j) {
        int r = ty * 8 + j;
        if (r < rows) {
            float4 o = make_float4(acc[j][0] + b.x, acc[j][1] + b.y,
                                   acc[j][2] + b.z, acc[j][3] + b.w);
            union { short4 s4; __half h[4]; } uh;
            uh.h[0] = __float2half(o.x); uh.h[1] = __float2half(o.y);
            uh.h[2] = __float2half(o.z); uh.h[3] = __float2half(o.w);
            *(short4*)&outEmb[(size_t)(r0 + r) * 128 + tx * 4] = uh.s4;
            s[0] += o.x; ss[0] += o.x * o.x;
            s[1] += o.y; ss[1] += o.y * o.y;
            s[2] += o.z; ss[2] += o.z * o.z;
            s[3] += o.w; ss[3] += o.w * o.w;
        }
    }
#pragma unroll
    for (int i = 0; i < 4; ++i) {
        atomicAdd(&sred[tx * 4 + i], s[i]);
        atomicAdd(&sred[128 + tx * 4 + i], ss[i]);
    }
    __syncthreads();
    atomicAdd(&stms[(blk & (STS - 1)) * 256 + threadIdx.x], sred[threadIdx.x]);
}

__global__ __launch_bounds__(256) void k_scan1(const int* __restrict__ deg, int* __restrict__ bsum) {
    __shared__ int sm[256];
    int i = blockIdx.x * 256 + threadIdx.x;
    sm[threadIdx.x] = (i < NN) ? deg[i] : 0;
    __syncthreads();
    for (int off = 128; off > 0; off >>= 1) {
        if (threadIdx.x < off) sm[threadIdx.x] += sm[threadIdx.x + off];
        __syncthreads();
    }
    if (threadIdx.x == 0) bsum[blockIdx.x] = sm[0];
}

__global__ __launch_bounds__(256) void k_scan2(const int* __restrict__ bsum,
                                               int* __restrict__ boff, int* __restrict__ rp) {
    __shared__ int sm[256];
    int t = threadIdx.x;
    int v = (t < NB) ? bsum[t] : 0;
    sm[t] = v;
    __syncthreads();
    for (int off = 1; off < 256; off <<= 1) {
        int u = (t >= off) ? sm[t - off] : 0;
        __syncthreads();
        sm[t] += u;
        __syncthreads();
    }
    if (t < NB) boff[t] = sm[t] - v;
    if (t == 255) rp[NN] = sm[255];
}

__global__ __launch_bounds__(256) void k_scan3(const int* __restrict__ deg,
                                               const int* __restrict__ boff,
                                               int* __restrict__ rp) {
    __shared__ int sm[256];
    int i = blockIdx.x * 256 + threadIdx.x;
    int t = threadIdx.x;
    int v = (i < NN) ? deg[i] : 0;
    sm[t] = v;
    __syncthreads();
    for (int off = 1; off < 256; off <<= 1) {
        int u = (t >= off) ? sm[t - off] : 0;
        __syncthreads();
        sm[t] += u;
        __syncthreads();
    }
    if (i < NN) rp[i] = boff[blockIdx.x] + sm[t] - v;
}

// atomic-free scatter: p = rp[d] + rank[e]; src-only
__global__ __launch_bounds__(256) void k_fill(const int* __restrict__ ei,
                                              const int* __restrict__ rp,
                                              const int* __restrict__ rank,
                                              int* __restrict__ esrc) {
    int tid = blockIdx.x * 256 + threadIdx.x;
    const int S = (NE + 3) / 4;
    if (tid >= S) return;
#pragma unroll
    for (int k = 0; k < 4; ++k) {
        int e = tid + k * S;
        if (e < NE) {
            int s = ei[e];
            int d = ei[NE + e];
            int p = rp[d] + rank[e];
            esrc[p] = s;
        }
    }
}

// ---------------- BN statistics over fp16 bC (slot-spread) -----------
__global__ __launch_bounds__(256) void k_stats(const __half* __restrict__ src, int nRows,
                                               float* __restrict__ st) {
    int c = threadIdx.x & 127;
    int sub = threadIdx.x >> 7;  // 0/1
    int r0 = blockIdx.x * 128;
    int rend = r0 + 128; if (rend > nRows) rend = nRows;
    float s = 0.f, ss = 0.f;
    for (int r = r0 + sub; r < rend; r += 2) {
        float v = __half2float(src[(size_t)r * 128 + c]);
        s += v; ss += v * v;
    }
    float* dst = st + (blockIdx.x & (STS - 1)) * 256;
    atomicAdd(&dst[c], s);
    atomicAdd(&dst[128 + c], ss);
}

// ------- pair-fused MFMA GEMM, 128-row tile with BN(+ReLU)+residual (fp16 res/xout) -
// src fp16; res fp16 (RES); xout fp16 (XOUT). st = STS slot-spread stats.
template <int OUTH0, int OUTH1, int RES, int XOUT>
__global__ __launch_bounds__(256) void k_gemm2bn(const __half* __restrict__ src,
                                                 const __half* __restrict__ res,
                                                 __half* __restrict__ xout,
                                                 const float* __restrict__ st,
                                                 const float* __restrict__ g,
                                                 const float* __restrict__ b,
                                                 const short* __restrict__ Wt0,
                                                 const short* __restrict__ Wt1,
                                                 const float* __restrict__ bias0,
                                                 const float* __restrict__ bias1,
                                                 void* __restrict__ out0,
                                                 void* __restrict__ out1, int nRows) {
    __shared__ short As[128 * 136];
    __shared__ short Bs[128 * 136];
    __shared__ float scsh[256];
    const float invn = 1.f / NN;
    if (threadIdx.x < 128) {
        int c = threadIdx.x;
        float s0v = 0.f, s1v = 0.f;
#pragma unroll 8
        for (int k2 = 0; k2 < STS; ++k2) {
            s0v += st[k2 * 256 + c];
            s1v += st[k2 * 256 + 128 + c];
        }
        float mean = s0v * invn;
        float var = fmaxf(s1v * invn - mean * mean, 0.f);
        float s = g[c] * rsqrtf(var + EPSB);
        scsh[c] = s;
        scsh[128 + c] = b[c] - mean * s;
    }
    {
        const int4* Wt4 = (const int4*)Wt0;
        for (int idx = threadIdx.x; idx < 2048; idx += 256) {
            int row = idx >> 4, c8 = idx & 15;
            *(int4*)&Bs[row * 136 + c8 * 8] = Wt4[idx];
        }
    }
    __syncthreads();  // scsh ready
    int r0 = blockIdx.x * 128;
    int rows = nRows - r0; if (rows > 128) rows = 128;
    for (int idx = threadIdx.x; idx < 2048; idx += 256) {
        int r = idx >> 4, c8 = idx & 15;
        short4 sa = {0, 0, 0, 0}, sb = {0, 0, 0, 0};
        if (r < rows) {
            size_t base = (size_t)(r0 + r) * 128 + c8 * 8;
            union { float4 f4; __half h[8]; } u;
            u.f4 = *(const float4*)&src[base];
            float4 v0 = make_float4(__half2float(u.h[0]), __half2float(u.h[1]),
                                    __half2float(u.h[2]), __half2float(u.h[3]));
            float4 v1 = make_float4(__half2float(u.h[4]), __half2float(u.h[5]),
                                    __half2float(u.h[6]), __half2float(u.h[7]));
            int c = c8 * 8;
            v0.x = fmaxf(v0.x * scsh[c + 0] + scsh[128 + c + 0], 0.f);
            v0.y = fmaxf(v0.y * scsh[c + 1] + scsh[128 + c + 1], 0.f);
            v0.z = fmaxf(v0.z * scsh[c + 2] + scsh[128 + c + 2], 0.f);
            v0.w = fmaxf(v0.w * scsh[c + 3] + scsh[128 + c + 3], 0.f);
            v1.x = fmaxf(v1.x * scsh[c + 4] + scsh[128 + c + 4], 0.f);
            v1.y = fmaxf(v1.y * scsh[c + 5] + scsh[128 + c + 5], 0.f);
            v1.z = fmaxf(v1.z * scsh[c + 6] + scsh[128 + c + 6], 0.f);
            v1.w = fmaxf(v1.w * scsh[c + 7] + scsh[128 + c + 7], 0.f);
            if (RES) {
                union { float4 f4; __half h[8]; } ur;
                ur.f4 = *(const float4*)&res[base];
                v0.x += __half2float(ur.h[0]); v0.y += __half2float(ur.h[1]);
                v0.z += __half2float(ur.h[2]); v0.w += __half2float(ur.h[3]);
                v1.x += __half2float(ur.h[4]); v1.y += __half2float(ur.h[5]);
                v1.z += __half2float(ur.h[6]); v1.w += __half2float(ur.h[7]);
            }
            if (XOUT) {
                union { float4 f4; __half h[8]; } uo;
                uo.h[0] = __float2half(v0.x); uo.h[1] = __float2half(v0.y);
                uo.h[2] = __float2half(v0.z); uo.h[3] = __float2half(v0.w);
                uo.h[4] = __float2half(v1.x); uo.h[5] = __float2half(v1.y);
                uo.h[6] = __float2half(v1.z); uo.h[7] = __float2half(v1.w);
                *(float4*)&xout[base] = uo.f4;
            }
            sa.x = f2bf(v0.x); sa.y = f2bf(v0.y); sa.z = f2bf(v0.z); sa.w = f2bf(v0.w);
            sb.x = f2bf(v1.x); sb.y = f2bf(v1.y); sb.z = f2bf(v1.z); sb.w = f2bf(v1.w);
        }
        *(short4*)&As[r * 136 + c8 * 8] = sa;
        *(short4*)&As[r * 136 + c8 * 8 + 4] = sb;
    }
    __syncthreads();
    int lane = threadIdx.x & 63, wave = threadIdx.x >> 6;
    int n16 = lane & 15, quad = lane >> 4;
    bf16x8 af[2][4];
#pragma unroll
    for (int rt = 0; rt < 2; ++rt)
#pragma unroll
        for (int kc = 0; kc < 4; ++kc)
            af[rt][kc] = *(const bf16x8*)&As[(wave * 32 + rt * 16 + n16) * 136 + kc * 32 + quad * 8];

    f32x4 acc[2][8];
#pragma unroll
    for (int rt = 0; rt < 2; ++rt)
#pragma unroll
        for (int ct = 0; ct < 8; ++ct) acc[rt][ct] = (f32x4){0.f, 0.f, 0.f, 0.f};
#pragma unroll
    for (int ct = 0; ct < 8; ++ct)
#pragma unroll
        for (int kc = 0; kc < 4; ++kc) {
            bf16x8 bf = *(const bf16x8*)&Bs[(ct * 16 + n16) * 136 + kc * 32 + quad * 8];
            acc[0][ct] = __builtin_amdgcn_mfma_f32_16x16x32_bf16(af[0][kc], bf, acc[0][ct], 0, 0, 0);
            acc[1][ct] = __builtin_amdgcn_mfma_f32_16x16x32_bf16(af[1][kc], bf, acc[1][ct], 0, 0, 0);
        }
#pragma unroll
    for (int ct = 0; ct < 8; ++ct) {
        int colI = ct * 16 + n16;
        float bv = bias0[colI];
#pragma unroll
        for (int rt = 0; rt < 2; ++rt)
#pragma unroll
            for (int reg = 0; reg < 4; ++reg) {
                int r = wave * 32 + rt * 16 + quad * 4 + reg;  // C/D: col=lane&15, row=quad*4+reg
                if (r < rows) {
                    float v = acc[rt][ct][reg] + bv;
                    if (OUTH0) ((__half*)out0)[(size_t)(r0 + r) * 128 + colI] = __float2half(v);
                    else       ((float*)out0)[(size_t)(r0 + r) * 128 + colI] = v;
                }
            }
    }
    __syncthreads();
    {
        const int4* Wt4 = (const int4*)Wt1;
        for (int idx = threadIdx.x; idx < 2048; idx += 256) {
            int row = idx >> 4, c8 = idx & 15;
            *(int4*)&Bs[row * 136 + c8 * 8] = Wt4[idx];
        }
    }
    __syncthreads();
#pragma unroll
    for (int rt = 0; rt < 2; ++rt)
#pragma unroll
        for (int ct = 0; ct < 8; ++ct) acc[rt][ct] = (f32x4){0.f, 0.f, 0.f, 0.f};
#pragma unroll
    for (int ct = 0; ct < 8; ++ct)
#pragma unroll
        for (int kc = 0; kc < 4; ++kc) {
            bf16x8 bf = *(const bf16x8*)&Bs[(ct * 16 + n16) * 136 + kc * 32 + quad * 8];
            acc[0][ct] = __builtin_amdgcn_mfma_f32_16x16x32_bf16(af[0][kc], bf, acc[0][ct], 0, 0, 0);
            acc[1][ct] = __builtin_amdgcn_mfma_f32_16x16x32_bf16(af[1][kc], bf, acc[1][ct], 0, 0, 0);
        }
#pragma unroll
    for (int ct = 0; ct < 8; ++ct) {
        int colI = ct * 16 + n16;
        float bv = bias1[colI];
#pragma unroll
        for (int rt = 0; rt < 2; ++rt)
#pragma unroll
            for (int reg = 0; reg < 4; ++reg) {
                int r = wave * 32 + rt * 16 + quad * 4 + reg;
                if (r < rows) {
                    float v = acc[rt][ct][reg] + bv;
                    if (OUTH1) ((__half*)out1)[(size_t)(r0 + r) * 128 + colI] = __float2half(v);
                    else       ((float*)out1)[(size_t)(r0 + r) * 128 + colI] = v;
                }
            }
    }
}

// ------- QUAD-fused MFMA GEMM (Q/K/V/S), 128-row tile; fp16 src/res/xout; KV intlv --
__global__ __launch_bounds__(256) void k_gemm4bn(const __half* __restrict__ src,
                                                 const __half* __restrict__ res,
                                                 __half* __restrict__ xout,
                                                 const float* __restrict__ st,
                                                 const float* __restrict__ g,
                                                 const float* __restrict__ b,
                                                 const short* __restrict__ Wt,
                                                 const float* __restrict__ bq,
                                                 const float* __restrict__ bk,
                                                 const float* __restrict__ bv,
                                                 const float* __restrict__ bs,
                                                 __half* __restrict__ oq,
                                                 __half* __restrict__ okv,
                                                 __half* __restrict__ os, int nRows) {
    __shared__ short As[128 * 136];
    __shared__ short Bs[128 * 136];
    __shared__ float scsh[256];
    const float invn = 1.f / NN;
    if (threadIdx.x < 128) {
        int c = threadIdx.x;
        float s0v = 0.f, s1v = 0.f;
#pragma unroll 8
        for (int k2 = 0; k2 < STS; ++k2) {
            s0v += st[k2 * 256 + c];
            s1v += st[k2 * 256 + 128 + c];
        }
        float mean = s0v * invn;
        float var = fmaxf(s1v * invn - mean * mean, 0.f);
        float s = g[c] * rsqrtf(var + EPSB);
        scsh[c] = s;
        scsh[128 + c] = b[c] - mean * s;
    }
    __syncthreads();  // scsh ready
    int r0 = blockIdx.x * 128;
    int rows = nRows - r0; if (rows > 128) rows = 128;
    for (int idx = threadIdx.x; idx < 2048; idx += 256) {
        int r = idx >> 4, c8 = idx & 15;
        short4 sa = {0, 0, 0, 0}, sb = {0, 0, 0, 0};
        if (r < rows) {
            size_t base = (size_t)(r0 + r) * 128 + c8 * 8;
            union { float4 f4; __half h[8]; } u;
            u.f4 = *(const float4*)&src[base];
            float4 v0 = make_float4(__half2float(u.h[0]), __half2float(u.h[1]),
                                    __half2float(u.h[2]), __half2float(u.h[3]));
            float4 v1 = make_float4(__half2float(u.h[4]), __half2float(u.h[5]),
                                    __half2float(u.h[6]), __half2float(u.h[7]));
            int c = c8 * 8;
            v0.x = fmaxf(v0.x * scsh[c + 0] + scsh[128 + c + 0], 0.f);
            v0.y = fmaxf(v0.y * scsh[c + 1] + scsh[128 + c + 1], 0.f);
            v0.z = fmaxf(v0.z * scsh[c + 2] + scsh[128 + c + 2], 0.f);
            v0.w = fmaxf(v0.w * scsh[c + 3] + scsh[128 + c + 3], 0.f);
            v1.x = fmaxf(v1.x * scsh[c + 4] + scsh[128 + c + 4], 0.f);
            v1.y = fmaxf(v1.y * scsh[c + 5] + scsh[128 + c + 5], 0.f);
            v1.z = fmaxf(v1.z * scsh[c + 6] + scsh[128 + c + 6], 0.f);
            v1.w = fmaxf(v1.w * scsh[c + 7] + scsh[128 + c + 7], 0.f);
            union { float4 f4; __half h[8]; } ur;
            ur.f4 = *(const float4*)&res[base];
            v0.x += __half2float(ur.h[0]); v0.y += __half2float(ur.h[1]);
            v0.z += __half2float(ur.h[2]); v0.w += __half2float(ur.h[3]);
            v1.x += __half2float(ur.h[4]); v1.y += __half2float(ur.h[5]);
            v1.z += __half2float(ur.h[6]); v1.w += __half2float(ur.h[7]);
            union { float4 f4; __half h[8]; } uo;
            uo.h[0] = __float2half(v0.x); uo.h[1] = __float2half(v0.y);
            uo.h[2] = __float2half(v0.z); uo.h[3] = __float2half(v0.w);
            uo.h[4] = __float2half(v1.x); uo.h[5] = __float2half(v1.y);
            uo.h[6] = __float2half(v1.z); uo.h[7] = __float2half(v1.w);
            *(float4*)&xout[base] = uo.f4;
            sa.x = f2bf(v0.x); sa.y = f2bf(v0.y); sa.z = f2bf(v0.z); sa.w = f2bf(v0.w);
            sb.x = f2bf(v1.x); sb.y = f2bf(v1.y); sb.z = f2bf(v1.z); sb.w = f2bf(v1.w);
        }
        *(short4*)&As[r * 136 + c8 * 8] = sa;
        *(short4*)&As[r * 136 + c8 * 8 + 4] = sb;
    }
    int lane = threadIdx.x & 63, wave = threadIdx.x >> 6;
    int n16 = lane & 15, quad = lane >> 4;
    bf16x8 af[2][4];
    bool afLoaded = false;
    for (int m = 0; m < 4; ++m) {
        {
            const int4* Wt4 = (const int4*)(Wt + (size_t)m * 16384);
            for (int idx = threadIdx.x; idx < 2048; idx += 256) {
                int row = idx >> 4, c8 = idx & 15;
                *(int4*)&Bs[row * 136 + c8 * 8] = Wt4[idx];
            }
        }
        __syncthreads();
        if (!afLoaded) {
            afLoaded = true;
#pragma unroll
            for (int rt = 0; rt < 2; ++rt)
#pragma unroll
                for (int kc = 0; kc < 4; ++kc)
                    af[rt][kc] = *(const bf16x8*)&As[(wave * 32 + rt * 16 + n16) * 136 + kc * 32 + quad * 8];
        }
        f32x4 acc[2][8];
#pragma unroll
        for (int rt = 0; rt < 2; ++rt)
#pragma unroll
            for (int ct = 0; ct < 8; ++ct) acc[rt][ct] = (f32x4){0.f, 0.f, 0.f, 0.f};
#pragma unroll
        for (int ct = 0; ct < 8; ++ct)
#pragma unroll
            for (int kc = 0; kc < 4; ++kc) {
                bf16x8 bf = *(const bf16x8*)&Bs[(ct * 16 + n16) * 136 + kc * 32 + quad * 8];
                acc[0][ct] = __builtin_amdgcn_mfma_f32_16x16x32_bf16(af[0][kc], bf, acc[0][ct], 0, 0, 0);
                acc[1][ct] = __builtin_amdgcn_mfma_f32_16x16x32_bf16(af[1][kc], bf, acc[1][ct], 0, 0, 0);
            }
        __half* om; int strd, off;
        const float* bm;
        if (m == 0)      { om = oq;  strd = 128; off = 0;   bm = bq; }
        else if (m == 1) { om = okv; strd = 256; off = 0;   bm = bk; }
        else if (m == 2) { om = okv; strd = 256; off = 128; bm = bv; }
        else             { om = os;  strd = 128; off = 0;   bm = bs; }
#pragma unroll
        for (int ct = 0; ct < 8; ++ct) {
            int colI = ct * 16 + n16;
            float bv2 = bm[colI];
#pragma unroll
            for (int rt = 0; rt < 2; ++rt)
#pragma unroll
                for (int reg = 0; reg < 4; ++reg) {
                    int r = wave * 32 + rt * 16 + quad * 4 + reg;
                    if (r < rows)
                        om[(size_t)(r0 + r) * strd + off + colI] = __float2half(acc[rt][ct][reg] + bv2);
                }
        }
        if (m < 3) __syncthreads();  // protect Bs before next stage
    }
}

// ---- FUSED GAT edge pass: quarter-wave per edge (r4-proven structure), fp16 out ----
__global__ __launch_bounds__(256) void k_gat_aggr(const __half* __restrict__ xl,
                                                  const __half* __restrict__ xr,
                                                  const float* __restrict__ att,
                                                  const float* __restrict__ gbias_l,
                                                  const int* __restrict__ rp,
                                                  const int* __restrict__ esrc,
                                                  __half* __restrict__ out) {
    int lane = threadIdx.x & 63;
    int node = blockIdx.x * 4 + (threadIdx.x >> 6);
    if (node >= NN) return;
    int q = lane >> 4;      // edge strand 0..3
    int l16 = lane & 15;
    int c8 = l16 * 8;
    float4 xrr = *(const float4*)&xr[(unsigned)node * 128u + c8];
    hv2 xrh[4] = {*(hv2*)&xrr.x, *(hv2*)&xrr.y, *(hv2*)&xrr.z, *(hv2*)&xrr.w};
    float4 atA = *(const float4*)&att[c8];
    float4 atB = *(const float4*)&att[c8 + 4];
    hv2 ath[4] = {{(_Float16)atA.x, (_Float16)atA.y}, {(_Float16)atA.z, (_Float16)atA.w},
                  {(_Float16)atB.x, (_Float16)atB.y}, {(_Float16)atB.z, (_Float16)atB.w}};
    const hv2 hz = {(_Float16)0.f, (_Float16)0.f};
    const hv2 hs = {(_Float16)LSLOPE, (_Float16)LSLOPE};
    int s0 = rp[node];
    int T = rp[node + 1] - s0 + 1;  // logical edge T-1 is the self loop
    float a[8] = {0.f, 0.f, 0.f, 0.f, 0.f, 0.f, 0.f, 0.f};
    float l = 0.f;
    auto body = [&](int j) {
        bool self = (j == T - 1);
        int srcn = self ? node : esrc[s0 + j];
        float4 raw = *(const float4*)&xl[(unsigned)srcn * 128u + c8];
        hv2 f[4] = {*(hv2*)&raw.x, *(hv2*)&raw.y, *(hv2*)&raw.z, *(hv2*)&raw.w};
        float p = 0.f;
#pragma unroll
        for (int k = 0; k < 4; ++k) {
            hv2 e = f[k] + xrh[k];
            hv2 lk = __builtin_elementwise_max(e, hz) + hs * __builtin_elementwise_min(e, hz);
            p = fdot2(lk, ath[k], p);
        }
        p += __shfl_xor(p, 1); p += __shfl_xor(p, 2);
        float w = __expf(p);
#pragma unroll
        for (int k = 0; k < 4; ++k) {
            a[2 * k] += w * (float)f[k].x;
            a[2 * k + 1] += w * (float)f[k].y;
        }
        l += w;
    };
    int j = q;
    for (; j + 12 < T; j += 16) { body(j); body(j + 4); body(j + 8); body(j + 12); }
    for (; j + 4 < T; j += 8) { body(j); body(j + 4); }
    for (; j < T; j += 4) body(j);
#pragma unroll
    for (int k = 0; k < 8; ++k) { a[k] += __shfl_xor(a[k], 16); a[k] += __shfl_xor(a[k], 32); }
    l += __shfl_xor(l, 16); l += __shfl_xor(l, 32);
    if (q == 0) {
        float inv = 1.f / (l + 1e-16f);
        float4 gb0 = *(const float4*)&gbias_l[c8];
        float4 gb1 = *(const float4*)&gbias_l[c8 + 4];
        union { float4 f4; __half h[8]; } u;
        u.h[0] = __float2half(a[0] * inv + gb0.x); u.h[1] = __float2half(a[1] * inv + gb0.y);
        u.h[2] = __float2half(a[2] * inv + gb0.z); u.h[3] = __float2half(a[3] * inv + gb0.w);
        u.h[4] = __float2half(a[4] * inv + gb1.x); u.h[5] = __float2half(a[5] * inv + gb1.y);
        u.h[6] = __float2half(a[6] * inv + gb1.z); u.h[7] = __float2half(a[7] * inv + gb1.w);
        *(float4*)&out[(unsigned)node * 128u + c8] = u.f4;
    }
}

// ---- FUSED Transformer edge pass: quarter-wave per edge, INTERLEAVED KV gather -----
__global__ __launch_bounds__(256) void k_trans_aggr(const __half* __restrict__ qh,
                                                    const __half* __restrict__ kv,
                                                    const __half* __restrict__ sT,
                                                    const int* __restrict__ rp,
                                                    const int* __restrict__ esrc,
                                                    __half* __restrict__ out) {
    int lane = threadIdx.x & 63;
    int node = blockIdx.x * 4 + (threadIdx.x >> 6);
    if (node >= NN) return;
    int q = lane >> 4;
    int l16 = lane & 15;
    int c8 = l16 * 8;
    float4 qr = *(const float4*)&qh[(unsigned)node * 128u + c8];
    const hv2 hinv = {(_Float16)INV_SQRT_C, (_Float16)INV_SQRT_C};
    hv2 qv[4] = {(*(hv2*)&qr.x) * hinv, (*(hv2*)&qr.y) * hinv,
                 (*(hv2*)&qr.z) * hinv, (*(hv2*)&qr.w) * hinv};
    int s0 = rp[node];
    int T = rp[node + 1] - s0;
    float a[8] = {0.f, 0.f, 0.f, 0.f, 0.f, 0.f, 0.f, 0.f};
    float l = 0.f;
    auto body = [&](int j) {
        int srcn = esrc[s0 + j];
        const __half* kvp = &kv[(unsigned)srcn * 256u + c8];
        float4 kraw = *(const float4*)kvp;          // K slice
        float4 vraw = *(const float4*)(kvp + 128);  // V slice (same 256B node block)
        hv2 kvv[4] = {*(hv2*)&kraw.x, *(hv2*)&kraw.y, *(hv2*)&kraw.z, *(hv2*)&kraw.w};
        float p = 0.f;
#pragma unroll
        for (int k = 0; k < 4; ++k) p = fdot2(kvv[k], qv[k], p);
        p += __shfl_xor(p, 1); p += __shfl_xor(p, 2);
        float w = __expf(p);
        hv2 vvv[4] = {*(hv2*)&vraw.x, *(hv2*)&vraw.y, *(hv2*)&vraw.z, *(hv2*)&vraw.w};
#pragma unroll
        for (int k = 0; k < 4; ++k) {
            a[2 * k] += w * (float)vvv[k].x;
            a[2 * k + 1] += w * (float)vvv[k].y;
        }
        l += w;
    };
    int j = q;
    for (; j + 12 < T; j += 16) { body(j); body(j + 4); body(j + 8); body(j + 12); }
    for (; j + 4 < T; j += 8) { body(j); body(j + 4); }
    for (; j < T; j += 4) body(j);
#pragma unroll
    for (int k = 0; k < 8; ++k) { a[k] += __shfl_xor(a[k], 16); a[k] += __shfl_xor(a[k], 32); }
    l += __shfl_xor(l, 16); l += __shfl_xor(l, 32);
    if (q == 0) {
        float inv = 1.f / (l + 1e-16f);
        float4 straw = *(const float4*)&sT[(unsigned)node * 128u + c8];
        hv2 st[4] = {*(hv2*)&straw.x, *(hv2*)&straw.y, *(hv2*)&straw.z, *(hv2*)&straw.w};
        union { float4 f4; __half h[8]; } u;
        u.h[0] = __float2half(a[0] * inv + (float)st[0].x);
        u.h[1] = __float2half(a[1] * inv + (float)st[0].y);
        u.h[2] = __float2half(a[2] * inv + (float)st[1].x);
        u.h[3] = __float2half(a[3] * inv + (float)st[1].y);
        u.h[4] = __float2half(a[4] * inv + (float)st[2].x);
        u.h[5] = __float2half(a[5] * inv + (float)st[2].y);
        u.h[6] = __float2half(a[6] * inv + (float)st[3].x);
        u.h[7] = __float2half(a[7] * inv + (float)st[3].y);
        *(float4*)&out[(unsigned)node * 128u + c8] = u.f4;
    }
}

// ---- pooling phase 1 WITH FUSED final BN: v = bn(src fp16) + res(fp16), sum/max ----
__global__ __launch_bounds__(256) void k_pool_part(const __half* __restrict__ src,
                                                   const __half* __restrict__ res,
                                                   const float* __restrict__ st,
                                                   const float* __restrict__ g,
                                                   const float* __restrict__ b,
                                                   const int* __restrict__ batch,
                                                   float* __restrict__ psum,
                                                   unsigned* __restrict__ pmax) {
    __shared__ int bs[64];
    __shared__ float sc_sh[128], sh_sh[128];
    int r0 = blockIdx.x * 64;
    if (threadIdx.x < 64) {
        int r = r0 + threadIdx.x;
        bs[threadIdx.x] = (r < NN) ? batch[r] : -1;
    }
    const float invn = 1.f / NN;
    if (threadIdx.x < 128) {
        int c2 = threadIdx.x;
        float s0v = 0.f, s1v = 0.f;
#pragma unroll 8
        for (int k2 = 0; k2 < STS; ++k2) {
            s0v += st[k2 * 256 + c2];
            s1v += st[k2 * 256 + 128 + c2];
        }
        float mean = s0v * invn;
        float var = fmaxf(s1v * invn - mean * mean, 0.f);
        float scv = g[c2] * rsqrtf(var + EPSB);
        sc_sh[c2] = scv;
        sh_sh[c2] = b[c2] - mean * scv;
    }
    __syncthreads();
    int c = threadIdx.x & 127;
    int sub = threadIdx.x >> 7;
    float scv = sc_sh[c];
    float shv = sh_sh[c];
    int curg = -1;
    float s = 0.f, fmx = -INFINITY;
    for (int i = sub; i < 64; i += 2) {
        int r = r0 + i;
        if (r >= NN) break;
        int gr = bs[i];
        if (gr != curg) {
            if (curg >= 0) {
                atomicAdd(&psum[curg * 128 + c], s);
                atomicMax(&pmax[curg * 128 + c], fenc(fmx));
            }
            curg = gr; s = 0.f; fmx = -INFINITY;
        }
        float v = __half2float(src[(size_t)r * 128 + c]) * scv + shv
                + __half2float(res[(size_t)r * 128 + c]);
        s += v; fmx = fmaxf(fmx, v);
    }
    if (curg >= 0) {
        atomicAdd(&psum[curg * 128 + c], s);
        atomicMax(&pmax[curg * 128 + c], fenc(fmx));
    }
}

// ---------------- pooling finalize + head1 GEMM + fused stats6 ----------------
__global__ __launch_bounds__(128) void k_pool_head1(const float* __restrict__ psum,
                                                    const unsigned* __restrict__ pmax,
                                                    const int* __restrict__ batch,
                                                    const float* __restrict__ W,
                                                    const float* __restrict__ b,
                                                    float* __restrict__ t1,
                                                    float* __restrict__ st6) {
    __shared__ float hr[256];
    __shared__ int se[2];
    int g = blockIdx.x;
    int t = threadIdx.x;
    if (t == 0) {
        int lo = 0, hi = NN;
        while (lo < hi) { int mid = (lo + hi) >> 1; if (batch[mid] < g) lo = mid + 1; else hi = mid; }
        se[0] = lo;
        hi = NN;
        while (lo < hi) { int mid = (lo + hi) >> 1; if (batch[mid] < g + 1) lo = mid + 1; else hi = mid; }
        se[1] = lo;
    }
    __syncthreads();
    int cnt = se[1] - se[0];
    float xm = psum[g * 128 + t] / fmaxf((float)cnt, 1.f);
    float xx = (cnt > 0) ? fdec(pmax[g * 128 + t]) : 0.f;
    hr[t] = xm;
    hr[128 + t] = xx;
    __syncthreads();
    float acc = b[t];
#pragma unroll 4
    for (int k = 0; k < 256; ++k) acc += hr[k] * W[k * 128 + t];
    t1[g * 128 + t] = acc;
    atomicAdd(&st6[t], acc);
    atomicAdd(&st6[128 + t], acc * acc);
}

__global__ __launch_bounds__(64) void k_head2(const float* __restrict__ t1,
                                              const float* __restrict__ st,
                                              const float* __restrict__ og,
                                              const float* __restrict__ obe,
                                              const float* __restrict__ W2,
                                              const float* __restrict__ b2,
                                              const float* __restrict__ W3,
                                              const float* __restrict__ b3,
                                              float* __restrict__ out) {
    __shared__ float v[128];
    int row = blockIdx.x, t = threadIdx.x;
    const float invn = 1.f / NG;
#pragma unroll
    for (int half = 0; half < 2; ++half) {
        int ch = t + half * 64;
        float mean = st[ch] * invn;
        float var = fmaxf(st[128 + ch] * invn - mean * mean, 0.f);
        float scv = og[ch] * rsqrtf(var + EPSB);
        float shv = obe[ch] - mean * scv;
        float a = t1[row * 128 + ch] * scv + shv;
        v[ch] = fmaxf(a, 0.f);
    }
    __syncthreads();
    float acc = b2[t];
#pragma unroll 4
    for (int k = 0; k < 128; ++k) acc += v[k] * W2[k * 64 + t];
    float p = fmaxf(acc, 0.f) * W3[t];
    p += __shfl_xor(p, 1); p += __shfl_xor(p, 2); p += __shfl_xor(p, 4);
    p += __shfl_xor(p, 8); p += __shfl_xor(p, 16); p += __shfl_xor(p, 32);
    if (t == 0) out[row] = p + b3[0];
}

// ---------------- launch ----------------
extern "C" void kernel_launch(void* const* d_in, const int* in_sizes, int n_in,
                              void* d_out, int out_size, void* d_ws, size_t ws_size,
                              hipStream_t stream) {
    const float* x_in   = (const float*)d_in[0];
    const int*   ei     = (const int*)d_in[1];
    const int*   batch  = (const int*)d_in[2];
    const float* emb_W  = (const float*)d_in[3];
    const float* emb_b  = (const float*)d_in[4];
    const float* emb_g  = (const float*)d_in[5];
    const float* emb_be = (const float*)d_in[6];
    const float* gWl    = (const float*)d_in[7];
    const float* gWr    = (const float*)d_in[8];
    const float* gbl    = (const float*)d_in[9];
    const float* gbr    = (const float*)d_in[10];
    const float* gatt   = (const float*)d_in[11];
    const float* gbias  = (const float*)d_in[12];
    const float* gg     = (const float*)d_in[13];
    const float* gbe    = (const float*)d_in[14];
    const float* tWq    = (const float*)d_in[15];
    const float* tWk    = (const float*)d_in[16];
    const float* tWv    = (const float*)d_in[17];
    const float* tWs    = (const float*)d_in[18];
    const float* tbq    = (const float*)d_in[19];
    const float* tbk    = (const float*)d_in[20];
    const float* tbv    = (const float*)d_in[21];
    const float* tbs    = (const float*)d_in[22];
    const float* tg     = (const float*)d_in[23];
    const float* tbe    = (const float*)d_in[24];
    const float* oW1    = (const float*)d_in[25];
    const float* ob1    = (const float*)d_in[26];
    const float* og     = (const float*)d_in[27];
    const float* obe    = (const float*)d_in[28];
    const float* oW2    = (const float*)d_in[29];
    const float* ob2    = (const float*)d_in[30];
    const float* oW3    = (const float*)d_in[31];
    const float* ob3    = (const float*)d_in[32];
    float* out = (float*)d_out;

    const size_t NDsz = (size_t)NN * 128;
    float* x     = (float*)d_ws;       // ping (fp16 view used; buffer oversized)
    float* bA    = x + NDsz;           // pong (fp16 view used)
    float* bC    = bA + NDsz;          // aggr output (fp16 view; also emb staging)
    float* stats = bC + NDsz;          // 7 * 256 floats (only slot 6 live now)
    float* hpool = stats + 7 * 256;    // 256*256 (dead; layout preserved)
    float* t1    = hpool + 65536;      // 256*128
    float* scb   = t1 + 32768;         // hosts rank (NE ints) + multi-slot stats
    __half* xlh  = (__half*)(scb + (size_t)(NE + NN) * 4);  // xl / S-skip
    __half* xrh  = xlh + NDsz;         // xr / Q
    __half* vh   = xrh + NDsz;         // start of interleaved KV region (NN*256 halfs)
    __half* sh   = vh + NDsz;
    short* Wt    = (short*)(sh + NDsz);  // 12 * 128*128 bf16 transposed
    int* deg     = (int*)(Wt + 12 * 16384);
    int* rp      = deg + NN;
    int* cursor  = rp + NN + 1;        // kept (dead) to preserve proven layout
    int2* edg    = (int2*)(cursor + NN);  // NE+64 slots; used as int src-list
    int* bsum    = (int*)(edg + NE + 64);
    int* boff    = bsum + 256;
    float* psum  = (float*)(boff + 256);            // NG*128
    unsigned* pmax = (unsigned*)(psum + NG * 128);  // NG*128
    int* rank    = (int*)scb;          // aliases scb, uses [0, NE)
    int* esrc    = (int*)edg;          // src-only edge list (padded past NE)
    // multi-slot stats: 6 regions x STS x 256 floats, in the slack after rank
    float* stms  = scb + NE;
    __half* bCh  = (__half*)bC;        // fp16 view of the aggregator buffer
    __half* xh   = (__half*)x;         // fp16 residual ping
    __half* bAh  = (__half*)bA;        // fp16 residual pong
    __half* kvh  = vh;                 // interleaved KV (node-major, 256 halfs/node)

    hipMemsetAsync(deg, 0, NN * sizeof(int), stream);
    hipMemsetAsync(stats + 6 * 256, 0, 256 * sizeof(float), stream);      // stats6
    hipMemsetAsync(stms, 0, 6 * STS * 256 * sizeof(float), stream);       // spread stats
    hipMemsetAsync(psum, 0, NG * 128 * 2 * sizeof(float), stream);        // psum + pmax

    const int gGemm = (NN + 127) / 128;  // 128-row tiles (r6-proven)
    const int gStat = (NN + 127) / 128;
    const int gNode = (NN + 3) / 4;
    const int gPool = (NN + 63) / 64;
    const int REG = STS * 256;  // stats region stride

    // MERGED front-end: deg atomics + weight prep + embedding GEMM (all independent)
    k_init<<<GD + 12 + GE, 256, 0, stream>>>(ei, deg, rank, gWl, gWr, tWq, tWk, tWv, tWs,
                                             Wt, x_in, emb_W, emb_b, bCh, stms + 0 * REG);

    // CSR by destination (rank-based; k_fill is atomic-free)
    k_scan1<<<NB, 256, 0, stream>>>(deg, bsum);
    k_scan2<<<1, 256, 0, stream>>>(bsum, boff, rp);
    k_scan3<<<NB, 256, 0, stream>>>(deg, boff, rp);
    k_fill<<<GQ, 256, 0, stream>>>(ei, rp, rank, esrc);

    // ping-pong fp16 residual buffers: residual source alternates xh <-> bAh
    k_gemm2bn<1, 1, 0, 1><<<gGemm, 256, 0, stream>>>(bCh, nullptr, xh, stms + 0 * REG, emb_g, emb_be,
                                                     Wt + (size_t)0 * 16384, Wt + (size_t)4 * 16384,
                                                     gbl + 0 * 128, gbr + 0 * 128, xlh, xrh, NN);
    k_gat_aggr<<<gNode, 256, 0, stream>>>(xlh, xrh, gatt + 0 * 128, gbias + 0 * 128, rp, esrc, bCh);
    k_stats<<<gStat, 256, 0, stream>>>(bCh, NN, stms + 1 * REG);
    k_gemm2bn<1, 1, 1, 1><<<gGemm, 256, 0, stream>>>(bCh, xh, bAh, stms + 1 * REG, gg + 0 * 128, gbe + 0 * 128,
                                                     Wt + (size_t)1 * 16384, Wt + (size_t)5 * 16384,
                                                     gbl + 1 * 128, gbr + 1 * 128, xlh, xrh, NN);
    k_gat_aggr<<<gNode, 256, 0, stream>>>(xlh, xrh, gatt + 1 * 128, gbias + 1 * 128, rp, esrc, bCh);
    k_stats<<<gStat, 256, 0, stream>>>(bCh, NN, stms + 2 * REG);
    k_gemm2bn<1, 1, 1, 1><<<gGemm, 256, 0, stream>>>(bCh, bAh, xh, stms + 2 * REG, gg + 1 * 128, gbe + 1 * 128,
                                                     Wt + (size_t)2 * 16384, Wt + (size_t)6 * 16384,
                                                     gbl + 2 * 128, gbr + 2 * 128, xlh, xrh, NN);
    k_gat_aggr<<<gNode, 256, 0, stream>>>(xlh, xrh, gatt + 2 * 128, gbias + 2 * 128, rp, esrc, bCh);
    k_stats<<<gStat, 256, 0, stream>>>(bCh, NN, stms + 3 * REG);
    k_gemm2bn<1, 1, 1, 1><<<gGemm, 256, 0, stream>>>(bCh, xh, bAh, stms + 3 * REG, gg + 2 * 128, gbe + 2 * 128,
                                                     Wt + (size_t)3 * 16384, Wt + (size_t)7 * 16384,
                                                     gbl + 3 * 128, gbr + 3 * 128, xlh, xrh, NN);
    k_gat_aggr<<<gNode, 256, 0, stream>>>(xlh, xrh, gatt + 3 * 128, gbias + 3 * 128, rp, esrc, bCh);
    k_stats<<<gStat, 256, 0, stream>>>(bCh, NN, stms + 4 * REG);

    // TransformerConv: ONE quad GEMM for Q / interleaved-KV / S (A staged once)
    k_gemm4bn<<<gGemm, 256, 0, stream>>>(bCh, bAh, xh, stms + 4 * REG, gg + 3 * 128, gbe + 3 * 128,
                                         Wt + (size_t)8 * 16384, tbq, tbk, tbv, tbs,
                                         xrh, kvh, xlh, NN);  // Q, KV, S
    k_trans_aggr<<<gNode, 256, 0, stream>>>(xrh, kvh, xlh, rp, esrc, bCh);
    k_stats<<<gStat, 256, 0, stream>>>(bCh, NN, stms + 5 * REG);

    // pooling (with fused final BN: v = bn(bC fp16) + xh fp16) + head
    k_pool_part<<<gPool, 256, 0, stream>>>(bCh, xh, stms + 5 * REG, tg, tbe, batch, psum, pmax);
    k_pool_head1<<<NG, 128, 0, stream>>>(psum, pmax, batch, oW1, ob1, t1, stats + 6 * 256);
    k_head2<<<NG, 64, 0, stream>>>(t1, stats + 6 * 256, og, obe, oW2, ob2, oW3, ob3, out);
}